// Round 1
// baseline (563.634 us; speedup 1.0000x reference)
//
#include <hip/hip_runtime.h>
#include <hip/hip_bf16.h>

typedef __attribute__((ext_vector_type(8))) short bf16x8;
typedef __attribute__((ext_vector_type(4))) float f32x4;

#define B_ 2
#define S_ 2048
#define H_ 2048
#define NH_ 16
#define NKV_ 8
#define HD_ 128
#define M_ (B_ * S_)                   // 4096
#define NQKV_ ((NH_ + 2 * NKV_) * HD_) // 4096
#define QK_SCALE 0.08838834764831845f  // 128^-0.5

__device__ __forceinline__ unsigned short f2bf(float f) {
  unsigned int u = __float_as_uint(f);
  u += 0x7fffu + ((u >> 16) & 1u);
  return (unsigned short)(u >> 16);
}
__device__ __forceinline__ float bf2f(unsigned short h) {
  return __uint_as_float(((unsigned int)h) << 16);
}
__device__ __forceinline__ void gload_lds16(const void* g, void* l) {
  __builtin_amdgcn_global_load_lds(
      (const __attribute__((address_space(1))) void*)g,
      (__attribute__((address_space(3))) void*)l, 16, 0, 0);
}

// ---------------- phase 1: prep ----------------
__global__ __launch_bounds__(256) void k_rmsnorm(
    const float* __restrict__ x, const float* __restrict__ w,
    unsigned short* __restrict__ out) {
  __shared__ float red[4];
  const int m = blockIdx.x;
  const int t = threadIdx.x;
  const float4* row = (const float4*)(x + (size_t)m * H_);
  float4 v0 = row[t];
  float4 v1 = row[t + 256];
  float ss = v0.x * v0.x + v0.y * v0.y + v0.z * v0.z + v0.w * v0.w +
             v1.x * v1.x + v1.y * v1.y + v1.z * v1.z + v1.w * v1.w;
#pragma unroll
  for (int mk = 1; mk < 64; mk <<= 1) ss += __shfl_xor(ss, mk);
  if ((t & 63) == 0) red[t >> 6] = ss;
  __syncthreads();
  ss = red[0] + red[1] + red[2] + red[3];
  const float sc = rsqrtf(ss * (1.0f / H_) + 1e-6f);
  const float4* wv = (const float4*)w;
  float4 w0 = wv[t], w1 = wv[t + 256];
  ushort4 o0, o1;
  o0.x = f2bf(v0.x * sc * w0.x);
  o0.y = f2bf(v0.y * sc * w0.y);
  o0.z = f2bf(v0.z * sc * w0.z);
  o0.w = f2bf(v0.w * sc * w0.w);
  o1.x = f2bf(v1.x * sc * w1.x);
  o1.y = f2bf(v1.y * sc * w1.y);
  o1.z = f2bf(v1.z * sc * w1.z);
  o1.w = f2bf(v1.w * sc * w1.w);
  ushort4* orow = (ushort4*)(out + (size_t)m * H_);
  orow[t] = o0;
  orow[t + 256] = o1;
}

__global__ __launch_bounds__(256) void k_f32_to_bf16(
    const float* __restrict__ in, unsigned short* __restrict__ out, int n4) {
  int idx = blockIdx.x * 256 + threadIdx.x;
  const int stride = gridDim.x * 256;
  for (; idx < n4; idx += stride) {
    float4 v = ((const float4*)in)[idx];
    ushort4 o;
    o.x = f2bf(v.x);
    o.y = f2bf(v.y);
    o.z = f2bf(v.z);
    o.w = f2bf(v.w);
    ((ushort4*)out)[idx] = o;
  }
}

__global__ __launch_bounds__(256) void k_rope_table(
    const int* __restrict__ positions, float* __restrict__ cos_t,
    float* __restrict__ sin_t) {
  int idx = blockIdx.x * 256 + threadIdx.x;
  if (idx >= B_ * S_ * 64) return;
  int d = idx & 63;
  int bs = idx >> 6;
  float pos = (float)positions[bs];
  float inv_freq = powf(10000.0f, -(float)(2 * d) * (1.0f / HD_));
  float ang = pos * inv_freq;
  cos_t[idx] = cosf(ang);
  sin_t[idx] = sinf(ang);
}

// ---------------- GEMM (A [M][K] bf16 x Bt [N][K] bf16) ----------------
// MODE 0: write bf16 C.  MODE 1: write f32 C += resid.
template <int MODE>
__global__ __launch_bounds__(256) void k_gemm_bt(
    const unsigned short* __restrict__ A, const unsigned short* __restrict__ Bt,
    void* __restrict__ Cout, const float* __restrict__ resid, int M, int N,
    int K) {
  __shared__ unsigned short sA[128 * 64];
  __shared__ unsigned short sB[128 * 64];
  const int tid = threadIdx.x;
  const int w = tid >> 6, l = tid & 63;
  const int lr = l & 15, lg = l >> 4;
  const int m0 = blockIdx.y * 128, n0 = blockIdx.x * 128;
  const int wm = (w >> 1) * 64, wn = (w & 1) * 64;
  f32x4 acc[4][4] = {};
  for (int k0 = 0; k0 < K; k0 += 64) {
#pragma unroll
    for (int i = 0; i < 4; ++i) {
      const int chunk = i * 256 + tid;
      const int row = chunk >> 3;          // 8 x 16B chunks per 64-elem row
      const int off = (chunk & 7) * 8;     // elements
      gload_lds16(A + (size_t)(m0 + row) * K + (k0 + off),
                  (char*)sA + (size_t)(i * 256 + w * 64) * 16);
      gload_lds16(Bt + (size_t)(n0 + row) * K + (k0 + off),
                  (char*)sB + (size_t)(i * 256 + w * 64) * 16);
    }
    __syncthreads();
#pragma unroll
    for (int kk = 0; kk < 64; kk += 32) {
      bf16x8 af[4], bfr[4];
#pragma unroll
      for (int i = 0; i < 4; ++i)
        af[i] = *(const bf16x8*)&sA[(wm + i * 16 + lr) * 64 + kk + lg * 8];
#pragma unroll
      for (int j = 0; j < 4; ++j)
        bfr[j] = *(const bf16x8*)&sB[(wn + j * 16 + lr) * 64 + kk + lg * 8];
#pragma unroll
      for (int i = 0; i < 4; ++i)
#pragma unroll
        for (int j = 0; j < 4; ++j)
          acc[i][j] = __builtin_amdgcn_mfma_f32_16x16x32_bf16(af[i], bfr[j],
                                                              acc[i][j], 0, 0, 0);
    }
    __syncthreads();
  }
#pragma unroll
  for (int i = 0; i < 4; ++i)
#pragma unroll
    for (int j = 0; j < 4; ++j)
#pragma unroll
      for (int r = 0; r < 4; ++r) {
        const int row = m0 + wm + i * 16 + lg * 4 + r;
        const int col = n0 + wn + j * 16 + lr;
        const size_t o = (size_t)row * N + col;
        if (MODE == 0)
          ((unsigned short*)Cout)[o] = f2bf(acc[i][j][r]);
        else
          ((float*)Cout)[o] = acc[i][j][r] + resid[o];
      }
}

// ---------------- phase 3: q/k norm + rope, split ----------------
__global__ __launch_bounds__(256) void k_postprocess(
    const unsigned short* __restrict__ qkv, const float* __restrict__ qw,
    const float* __restrict__ kw, const float* __restrict__ cos_t,
    const float* __restrict__ sin_t, unsigned short* __restrict__ qb,
    unsigned short* __restrict__ kb, unsigned short* __restrict__ vb) {
  const int m = blockIdx.x;
  const int b = m >> 11, s = m & (S_ - 1);
  const int w = threadIdx.x >> 6, l = threadIdx.x & 63;
  const unsigned short* row = qkv + (size_t)m * NQKV_;
  const float c = cos_t[(size_t)m * 64 + l];
  const float sn = sin_t[(size_t)m * 64 + l];
  for (int hh = w * 8; hh < w * 8 + 8; ++hh) {
    int base, type;
    unsigned short* out;
    const float* nw;
    if (hh < NH_) {
      type = 0;
      base = hh * HD_;
      out = qb + ((size_t)(b * NH_ + hh) * S_ + s) * HD_;
      nw = qw;
    } else if (hh < NH_ + NKV_) {
      int kh = hh - NH_;
      type = 1;
      base = NH_ * HD_ + kh * HD_;
      out = kb + ((size_t)(b * NKV_ + kh) * S_ + s) * HD_;
      nw = kw;
    } else {
      int kh = hh - NH_ - NKV_;
      type = 2;
      base = (NH_ + NKV_) * HD_ + kh * HD_;
      out = vb + ((size_t)(b * NKV_ + kh) * S_ + s) * HD_;
      nw = nullptr;
    }
    unsigned short r1 = row[base + l];
    unsigned short r2 = row[base + 64 + l];
    if (type == 2) {  // v: pass through
      out[l] = r1;
      out[64 + l] = r2;
      continue;
    }
    float x1 = bf2f(r1), x2 = bf2f(r2);
    float ss = x1 * x1 + x2 * x2;
#pragma unroll
    for (int mk = 1; mk < 64; mk <<= 1) ss += __shfl_xor(ss, mk);
    float sc = rsqrtf(ss * (1.0f / HD_) + 1e-6f);
    float y1 = x1 * sc * nw[l];
    float y2 = x2 * sc * nw[64 + l];
    float o1 = y1 * c - y2 * sn;
    float o2 = y2 * c + y1 * sn;
    if (type == 0) {
      o1 *= QK_SCALE;
      o2 *= QK_SCALE;
    }
    out[l] = f2bf(o1);
    out[64 + l] = f2bf(o2);
  }
}

// ---------------- phase 3b: V -> V^T ----------------
__global__ __launch_bounds__(256) void k_transpose_v(
    const unsigned short* __restrict__ in,  // [BH][S][HD]
    unsigned short* __restrict__ out) {     // [BH][HD][S]
  __shared__ unsigned short tile[32][33];
  const int bx = blockIdx.x, by = blockIdx.y, bz = blockIdx.z;
  const unsigned short* src = in + (size_t)bz * S_ * HD_;
  unsigned short* dst = out + (size_t)bz * S_ * HD_;
  const int tx = threadIdx.x & 31, ty = threadIdx.x >> 5;
#pragma unroll
  for (int i = ty; i < 32; i += 8)
    tile[i][tx] = src[(size_t)(bx * 32 + i) * HD_ + by * 32 + tx];
  __syncthreads();
#pragma unroll
  for (int i = ty; i < 32; i += 8)
    dst[(size_t)(by * 32 + i) * S_ + bx * 32 + tx] = tile[tx][i];
}

// ---------------- phase 4: causal GQA flash attention ----------------
__global__ __launch_bounds__(256) void k_attn(
    const unsigned short* __restrict__ Q,   // [B*NH][S][HD] (pre-scaled)
    const unsigned short* __restrict__ K,   // [B*NKV][S][HD]
    const unsigned short* __restrict__ VT,  // [B*NKV][HD][S]
    unsigned short* __restrict__ Oa) {      // [M][NH*HD]
  __shared__ unsigned short kt[64 * 128];
  __shared__ unsigned short vt[128 * 64];
  __shared__ unsigned short pl[4 * 16 * 64];
  const int bh = blockIdx.y;
  const int b = bh >> 4, h = bh & 15;
  const int kvh = b * NKV_ + (h >> 1);
  const int q0 = blockIdx.x * 64;
  const int w = threadIdx.x >> 6, l = threadIdx.x & 63;
  const int lr = l & 15, lg = l >> 4;
  const unsigned short* Qp = Q + ((size_t)bh * S_ + q0 + w * 16) * HD_;
  bf16x8 qf[4];
#pragma unroll
  for (int t = 0; t < 4; ++t)
    qf[t] = *(const bf16x8*)(Qp + (size_t)lr * HD_ + t * 32 + lg * 8);
  f32x4 ao[8] = {};
  float mrow[4], lrow[4];
#pragma unroll
  for (int r = 0; r < 4; ++r) {
    mrow[r] = -1e30f;
    lrow[r] = 0.f;
  }
  const int tmax = q0 / 64;
  const unsigned short* Kp = K + (size_t)kvh * S_ * HD_;
  const unsigned short* Vp = VT + (size_t)kvh * HD_ * S_;
  unsigned short* pw = pl + w * 16 * 64;
  for (int t = 0; t <= tmax; ++t) {
    const int k0 = t * 64;
#pragma unroll
    for (int i = 0; i < 4; ++i) {
      const int chunk = i * 256 + threadIdx.x;
      gload_lds16(Kp + (size_t)(k0 + (chunk >> 4)) * HD_ + (chunk & 15) * 8,
                  (char*)kt + (size_t)(i * 256 + w * 64) * 16);
      gload_lds16(Vp + (size_t)(chunk >> 3) * S_ + k0 + (chunk & 7) * 8,
                  (char*)vt + (size_t)(i * 256 + w * 64) * 16);
    }
    __syncthreads();
    f32x4 sc[4] = {};
#pragma unroll
    for (int j = 0; j < 4; ++j)
#pragma unroll
      for (int tt = 0; tt < 4; ++tt) {
        bf16x8 kf = *(const bf16x8*)&kt[(j * 16 + lr) * 128 + tt * 32 + lg * 8];
        sc[j] = __builtin_amdgcn_mfma_f32_16x16x32_bf16(qf[tt], kf, sc[j], 0, 0, 0);
      }
    if (t == tmax) {  // diagonal tile: mask kv > q
      const int kvc = k0 + lr;
      const int qg = q0 + w * 16 + lg * 4;
#pragma unroll
      for (int j = 0; j < 4; ++j)
#pragma unroll
        for (int r = 0; r < 4; ++r)
          if (kvc + j * 16 > qg + r) sc[j][r] = -1e30f;
    }
    float resc[4], rs[4];
#pragma unroll
    for (int r = 0; r < 4; ++r) {
      float v = fmaxf(fmaxf(sc[0][r], sc[1][r]), fmaxf(sc[2][r], sc[3][r]));
#pragma unroll
      for (int mk = 1; mk < 16; mk <<= 1) v = fmaxf(v, __shfl_xor(v, mk));
      const float mn = fmaxf(mrow[r], v);
      resc[r] = __expf(mrow[r] - mn);
      mrow[r] = mn;
      rs[r] = 0.f;
    }
    unsigned short pb[4][4];
#pragma unroll
    for (int j = 0; j < 4; ++j)
#pragma unroll
      for (int r = 0; r < 4; ++r) {
        float p = __expf(sc[j][r] - mrow[r]);
        rs[r] += p;
        pb[j][r] = f2bf(p);
      }
#pragma unroll
    for (int r = 0; r < 4; ++r) {
      float v = rs[r];
#pragma unroll
      for (int mk = 1; mk < 16; mk <<= 1) v += __shfl_xor(v, mk);
      lrow[r] = lrow[r] * resc[r] + v;
    }
#pragma unroll
    for (int j = 0; j < 4; ++j)
#pragma unroll
      for (int r = 0; r < 4; ++r)
        pw[(lg * 4 + r) * 64 + j * 16 + lr] = pb[j][r];
#pragma unroll
    for (int f = 0; f < 8; ++f)
#pragma unroll
      for (int r = 0; r < 4; ++r) ao[f][r] *= resc[r];
#pragma unroll
    for (int ks = 0; ks < 2; ++ks) {
      bf16x8 pf = *(const bf16x8*)&pw[lr * 64 + ks * 32 + lg * 8];
#pragma unroll
      for (int dj = 0; dj < 8; ++dj) {
        bf16x8 vf = *(const bf16x8*)&vt[(dj * 16 + lr) * 64 + ks * 32 + lg * 8];
        ao[dj] = __builtin_amdgcn_mfma_f32_16x16x32_bf16(pf, vf, ao[dj], 0, 0, 0);
      }
    }
    __syncthreads();
  }
  float inv[4];
#pragma unroll
  for (int r = 0; r < 4; ++r) inv[r] = 1.0f / lrow[r];
#pragma unroll
  for (int dj = 0; dj < 8; ++dj)
#pragma unroll
    for (int r = 0; r < 4; ++r) {
      const int sg = q0 + w * 16 + lg * 4 + r;
      const size_t o =
          ((size_t)b * S_ + sg) * (NH_ * HD_) + h * HD_ + dj * 16 + lr;
      Oa[o] = f2bf(ao[dj][r] * inv[r]);
    }
}

extern "C" void kernel_launch(void* const* d_in, const int* in_sizes, int n_in,
                              void* d_out, int out_size, void* d_ws,
                              size_t ws_size, hipStream_t stream) {
  const int* positions = (const int*)d_in[0];
  const float* hidden = (const float*)d_in[1];
  const float* residual = (const float*)d_in[2];
  const float* ln_w = (const float*)d_in[3];
  const float* qkv_w = (const float*)d_in[4];
  const float* o_w = (const float*)d_in[5];
  const float* q_nw = (const float*)d_in[6];
  const float* k_nw = (const float*)d_in[7];

  char* ws = (char*)d_ws;
  const size_t SZ_XN = (size_t)M_ * H_ * 2;            // 16 MiB
  const size_t SZ_QKVW = (size_t)NQKV_ * H_ * 2;       // 16 MiB
  const size_t SZ_OW = (size_t)H_ * (NH_ * HD_) * 2;   // 8 MiB
  const size_t SZ_QKV = (size_t)M_ * NQKV_ * 2;        // 32 MiB
  const size_t SZ_KB = (size_t)B_ * NKV_ * S_ * HD_ * 2;  // 8 MiB
  const size_t SZ_COS = (size_t)B_ * S_ * 64 * 4;      // 1 MiB

  // phase-overlapped layout (regions reused only after their last reader)
  unsigned short* xn = (unsigned short*)(ws);
  unsigned short* q_buf = (unsigned short*)(ws);            // reuse xn
  unsigned short* qkvw_bf = (unsigned short*)(ws + SZ_XN);
  unsigned short* k_buf = (unsigned short*)(ws + SZ_XN);    // reuse qkvw
  unsigned short* v_buf = (unsigned short*)(ws + SZ_XN + SZ_KB);
  unsigned short* owbf = (unsigned short*)(ws + SZ_XN + SZ_QKVW);
  unsigned short* qkv_bf = (unsigned short*)(ws + SZ_XN + SZ_QKVW + SZ_OW);
  unsigned short* attn_o = qkv_bf;                          // reuse qkv
  unsigned short* vt_buf =
      (unsigned short*)(ws + SZ_XN + SZ_QKVW + SZ_OW + SZ_QKV);
  float* cos_t = (float*)(ws + SZ_XN + SZ_QKVW + SZ_OW + SZ_QKV + SZ_KB);
  float* sin_t = (float*)((char*)cos_t + SZ_COS);

  k_rmsnorm<<<M_, 256, 0, stream>>>(hidden, ln_w, xn);
  k_f32_to_bf16<<<2048, 256, 0, stream>>>(qkv_w, qkvw_bf,
                                          (int)(SZ_QKVW / 2 / 4));
  k_f32_to_bf16<<<1024, 256, 0, stream>>>(o_w, owbf, (int)(SZ_OW / 2 / 4));
  k_rope_table<<<(B_ * S_ * 64) / 256, 256, 0, stream>>>(positions, cos_t,
                                                         sin_t);
  k_gemm_bt<0><<<dim3(NQKV_ / 128, M_ / 128), 256, 0, stream>>>(
      xn, qkvw_bf, qkv_bf, nullptr, M_, NQKV_, H_);
  k_postprocess<<<M_, 256, 0, stream>>>(qkv_bf, q_nw, k_nw, cos_t, sin_t,
                                        q_buf, k_buf, v_buf);
  k_transpose_v<<<dim3(S_ / 32, HD_ / 32, B_ * NKV_), 256, 0, stream>>>(v_buf,
                                                                        vt_buf);
  k_attn<<<dim3(S_ / 64, B_ * NH_), 256, 0, stream>>>(q_buf, k_buf, vt_buf,
                                                      attn_o);
  k_gemm_bt<1><<<dim3((NH_ * HD_) / 128, M_ / 128), 256, 0, stream>>>(
      attn_o, owbf, d_out, residual, M_, NH_ * HD_, H_);
}

// Round 2
// 288.385 us; speedup vs baseline: 1.9544x; 1.9544x over previous
//
#include <hip/hip_runtime.h>
#include <hip/hip_bf16.h>

typedef __attribute__((ext_vector_type(8))) short bf16x8;
typedef __attribute__((ext_vector_type(4))) float f32x4;

#define B_ 2
#define S_ 2048
#define H_ 2048
#define NH_ 16
#define NKV_ 8
#define HD_ 128
#define M_ (B_ * S_)                   // 4096
#define NQKV_ ((NH_ + 2 * NKV_) * HD_) // 4096
#define QK_SCALE 0.08838834764831845f  // 128^-0.5

__device__ __forceinline__ unsigned short f2bf(float f) {
  unsigned int u = __float_as_uint(f);
  u += 0x7fffu + ((u >> 16) & 1u);
  return (unsigned short)(u >> 16);
}
__device__ __forceinline__ float bf2f(unsigned short h) {
  return __uint_as_float(((unsigned int)h) << 16);
}
__device__ __forceinline__ void gload_lds16(const void* g, void* l) {
  __builtin_amdgcn_global_load_lds(
      (const __attribute__((address_space(1))) void*)g,
      (__attribute__((address_space(3))) void*)l, 16, 0, 0);
}

// ---------------- phase 1: prep ----------------
__global__ __launch_bounds__(256) void k_rmsnorm(
    const float* __restrict__ x, const float* __restrict__ w,
    unsigned short* __restrict__ out) {
  __shared__ float red[4];
  const int m = blockIdx.x;
  const int t = threadIdx.x;
  const float4* row = (const float4*)(x + (size_t)m * H_);
  float4 v0 = row[t];
  float4 v1 = row[t + 256];
  float ss = v0.x * v0.x + v0.y * v0.y + v0.z * v0.z + v0.w * v0.w +
             v1.x * v1.x + v1.y * v1.y + v1.z * v1.z + v1.w * v1.w;
#pragma unroll
  for (int mk = 1; mk < 64; mk <<= 1) ss += __shfl_xor(ss, mk);
  if ((t & 63) == 0) red[t >> 6] = ss;
  __syncthreads();
  ss = red[0] + red[1] + red[2] + red[3];
  const float sc = rsqrtf(ss * (1.0f / H_) + 1e-6f);
  const float4* wv = (const float4*)w;
  float4 w0 = wv[t], w1 = wv[t + 256];
  ushort4 o0, o1;
  o0.x = f2bf(v0.x * sc * w0.x);
  o0.y = f2bf(v0.y * sc * w0.y);
  o0.z = f2bf(v0.z * sc * w0.z);
  o0.w = f2bf(v0.w * sc * w0.w);
  o1.x = f2bf(v1.x * sc * w1.x);
  o1.y = f2bf(v1.y * sc * w1.y);
  o1.z = f2bf(v1.z * sc * w1.z);
  o1.w = f2bf(v1.w * sc * w1.w);
  ushort4* orow = (ushort4*)(out + (size_t)m * H_);
  orow[t] = o0;
  orow[t + 256] = o1;
}

__global__ __launch_bounds__(256) void k_f32_to_bf16(
    const float* __restrict__ in, unsigned short* __restrict__ out, int n4) {
  int idx = blockIdx.x * 256 + threadIdx.x;
  const int stride = gridDim.x * 256;
  for (; idx < n4; idx += stride) {
    float4 v = ((const float4*)in)[idx];
    ushort4 o;
    o.x = f2bf(v.x);
    o.y = f2bf(v.y);
    o.z = f2bf(v.z);
    o.w = f2bf(v.w);
    ((ushort4*)out)[idx] = o;
  }
}

__global__ __launch_bounds__(256) void k_rope_table(
    const int* __restrict__ positions, float* __restrict__ cos_t,
    float* __restrict__ sin_t) {
  int idx = blockIdx.x * 256 + threadIdx.x;
  if (idx >= B_ * S_ * 64) return;
  int d = idx & 63;
  int bs = idx >> 6;
  float pos = (float)positions[bs];
  float inv_freq = powf(10000.0f, -(float)(2 * d) * (1.0f / HD_));
  float ang = pos * inv_freq;
  cos_t[idx] = cosf(ang);
  sin_t[idx] = sinf(ang);
}

// ---------------- GEMM (A [M][K] bf16 x Bt [N][K] bf16) ----------------
// MODE 0: write bf16 C.  MODE 1: write f32 C += resid.
template <int MODE>
__global__ __launch_bounds__(256) void k_gemm_bt(
    const unsigned short* __restrict__ A, const unsigned short* __restrict__ Bt,
    void* __restrict__ Cout, const float* __restrict__ resid, int M, int N,
    int K) {
  __shared__ unsigned short sA[128 * 64];
  __shared__ unsigned short sB[128 * 64];
  const int tid = threadIdx.x;
  const int w = tid >> 6, l = tid & 63;
  const int lr = l & 15, lg = l >> 4;
  const int m0 = blockIdx.y * 128, n0 = blockIdx.x * 128;
  const int wm = (w >> 1) * 64, wn = (w & 1) * 64;
  f32x4 acc[4][4] = {};
  for (int k0 = 0; k0 < K; k0 += 64) {
#pragma unroll
    for (int i = 0; i < 4; ++i) {
      const int chunk = i * 256 + tid;
      const int row = chunk >> 3;          // 8 x 16B chunks per 64-elem row
      const int off = (chunk & 7) * 8;     // elements
      gload_lds16(A + (size_t)(m0 + row) * K + (k0 + off),
                  (char*)sA + (size_t)(i * 256 + w * 64) * 16);
      gload_lds16(Bt + (size_t)(n0 + row) * K + (k0 + off),
                  (char*)sB + (size_t)(i * 256 + w * 64) * 16);
    }
    __syncthreads();
#pragma unroll
    for (int kk = 0; kk < 64; kk += 32) {
      bf16x8 af[4], bfr[4];
#pragma unroll
      for (int i = 0; i < 4; ++i)
        af[i] = *(const bf16x8*)&sA[(wm + i * 16 + lr) * 64 + kk + lg * 8];
#pragma unroll
      for (int j = 0; j < 4; ++j)
        bfr[j] = *(const bf16x8*)&sB[(wn + j * 16 + lr) * 64 + kk + lg * 8];
#pragma unroll
      for (int i = 0; i < 4; ++i)
#pragma unroll
        for (int j = 0; j < 4; ++j)
          acc[i][j] = __builtin_amdgcn_mfma_f32_16x16x32_bf16(af[i], bfr[j],
                                                              acc[i][j], 0, 0, 0);
    }
    __syncthreads();
  }
#pragma unroll
  for (int i = 0; i < 4; ++i)
#pragma unroll
    for (int j = 0; j < 4; ++j)
#pragma unroll
      for (int r = 0; r < 4; ++r) {
        const int row = m0 + wm + i * 16 + lg * 4 + r;
        const int col = n0 + wn + j * 16 + lr;
        const size_t o = (size_t)row * N + col;
        if (MODE == 0)
          ((unsigned short*)Cout)[o] = f2bf(acc[i][j][r]);
        else
          ((float*)Cout)[o] = acc[i][j][r] + resid[o];
      }
}

// ---------------- phase 3: q/k norm + rope, split ----------------
__global__ __launch_bounds__(256) void k_postprocess(
    const unsigned short* __restrict__ qkv, const float* __restrict__ qw,
    const float* __restrict__ kw, const float* __restrict__ cos_t,
    const float* __restrict__ sin_t, unsigned short* __restrict__ qb,
    unsigned short* __restrict__ kb, unsigned short* __restrict__ vb) {
  const int m = blockIdx.x;
  const int b = m >> 11, s = m & (S_ - 1);
  const int w = threadIdx.x >> 6, l = threadIdx.x & 63;
  const unsigned short* row = qkv + (size_t)m * NQKV_;
  const float c = cos_t[(size_t)m * 64 + l];
  const float sn = sin_t[(size_t)m * 64 + l];
  for (int hh = w * 8; hh < w * 8 + 8; ++hh) {
    int base, type;
    unsigned short* out;
    const float* nw;
    if (hh < NH_) {
      type = 0;
      base = hh * HD_;
      out = qb + ((size_t)(b * NH_ + hh) * S_ + s) * HD_;
      nw = qw;
    } else if (hh < NH_ + NKV_) {
      int kh = hh - NH_;
      type = 1;
      base = NH_ * HD_ + kh * HD_;
      out = kb + ((size_t)(b * NKV_ + kh) * S_ + s) * HD_;
      nw = kw;
    } else {
      int kh = hh - NH_ - NKV_;
      type = 2;
      base = (NH_ + NKV_) * HD_ + kh * HD_;
      out = vb + ((size_t)(b * NKV_ + kh) * S_ + s) * HD_;
      nw = nullptr;
    }
    unsigned short r1 = row[base + l];
    unsigned short r2 = row[base + 64 + l];
    if (type == 2) {  // v: pass through
      out[l] = r1;
      out[64 + l] = r2;
      continue;
    }
    float x1 = bf2f(r1), x2 = bf2f(r2);
    float ss = x1 * x1 + x2 * x2;
#pragma unroll
    for (int mk = 1; mk < 64; mk <<= 1) ss += __shfl_xor(ss, mk);
    float sc = rsqrtf(ss * (1.0f / HD_) + 1e-6f);
    float y1 = x1 * sc * nw[l];
    float y2 = x2 * sc * nw[64 + l];
    float o1 = y1 * c - y2 * sn;
    float o2 = y2 * c + y1 * sn;
    if (type == 0) {
      o1 *= QK_SCALE;
      o2 *= QK_SCALE;
    }
    out[l] = f2bf(o1);
    out[64 + l] = f2bf(o2);
  }
}

// ---------------- phase 3b: V -> V^T ----------------
__global__ __launch_bounds__(256) void k_transpose_v(
    const unsigned short* __restrict__ in,  // [BH][S][HD]
    unsigned short* __restrict__ out) {     // [BH][HD][S]
  __shared__ unsigned short tile[32][33];
  const int bx = blockIdx.x, by = blockIdx.y, bz = blockIdx.z;
  const unsigned short* src = in + (size_t)bz * S_ * HD_;
  unsigned short* dst = out + (size_t)bz * S_ * HD_;
  const int tx = threadIdx.x & 31, ty = threadIdx.x >> 5;
#pragma unroll
  for (int i = ty; i < 32; i += 8)
    tile[i][tx] = src[(size_t)(bx * 32 + i) * HD_ + by * 32 + tx];
  __syncthreads();
#pragma unroll
  for (int i = ty; i < 32; i += 8)
    dst[(size_t)(by * 32 + i) * S_ + bx * 32 + tx] = tile[tx][i];
}

// ---------------- phase 4: causal GQA flash attention ----------------
// Balanced pairing: block x handles q-tiles xa=x and xb=31-x (constant 33
// tile-steps/block), sharing one K/V staging pass. K/V/P LDS tiles are
// XOR-swizzled (chunk d = p ^ (row&7)) via pre-swizzled global source for
// global_load_lds (rule #21) + matching swizzled reads.
__global__ __launch_bounds__(256, 2) void k_attn(
    const unsigned short* __restrict__ Q,   // [B*NH][S][HD] (pre-scaled)
    const unsigned short* __restrict__ K,   // [B*NKV][S][HD]
    const unsigned short* __restrict__ VT,  // [B*NKV][HD][S]
    unsigned short* __restrict__ Oa) {      // [M][NH*HD]
  __shared__ unsigned short kt[2][64 * 128];
  __shared__ unsigned short vt[2][128 * 64];
  __shared__ unsigned short pls[2][4 * 16 * 64];
  const int bh = blockIdx.y;
  const int b = bh >> 4, h = bh & 15;
  const int kvh = b * NKV_ + (h >> 1);
  const int xa = blockIdx.x;       // 0..15
  const int xb = 31 - xa;          // 16..31
  const int q0a = xa * 64, q0b = xb * 64;
  const int w = threadIdx.x >> 6, l = threadIdx.x & 63;
  const int lr = l & 15, lg = l >> 4;

  bf16x8 qfA[4], qfB[4];
  {
    const unsigned short* Qp = Q + ((size_t)bh * S_ + q0a + w * 16) * HD_;
#pragma unroll
    for (int tt = 0; tt < 4; ++tt)
      qfA[tt] = *(const bf16x8*)(Qp + (size_t)lr * HD_ + tt * 32 + lg * 8);
  }
  {
    const unsigned short* Qp = Q + ((size_t)bh * S_ + q0b + w * 16) * HD_;
#pragma unroll
    for (int tt = 0; tt < 4; ++tt)
      qfB[tt] = *(const bf16x8*)(Qp + (size_t)lr * HD_ + tt * 32 + lg * 8);
  }
  f32x4 aoA[8] = {}, aoB[8] = {};
  float mA[4], lA[4], mB[4], lB[4];
#pragma unroll
  for (int r = 0; r < 4; ++r) {
    mA[r] = -1e30f;
    lA[r] = 0.f;
    mB[r] = -1e30f;
    lB[r] = 0.f;
  }
  const unsigned short* Kp = K + (size_t)kvh * S_ * HD_;
  const unsigned short* Vp = VT + (size_t)kvh * HD_ * S_;

  auto stage = [&](int t, int bufi) {
    const int k0 = t * 64;
#pragma unroll
    for (int i = 0; i < 4; ++i) {
      const int chunk = i * 256 + threadIdx.x;
      {
        const int r = chunk >> 4, p = chunk & 15;
        const int d = p ^ (r & 7);
        gload_lds16(Kp + (size_t)(k0 + r) * HD_ + d * 8,
                    (char*)kt[bufi] + (size_t)(i * 256 + w * 64) * 16);
      }
      {
        const int r = chunk >> 3, p = chunk & 7;
        const int d = p ^ (r & 7);
        gload_lds16(Vp + (size_t)r * S_ + k0 + d * 8,
                    (char*)vt[bufi] + (size_t)(i * 256 + w * 64) * 16);
      }
    }
  };

  auto process = [&](int t, int bufi, const bf16x8 (&qf)[4], f32x4 (&ao)[8],
                     float (&mrow)[4], float (&lrow)[4], unsigned short* pw,
                     int q0t, bool diag) {
    const unsigned short* ktb = kt[bufi];
    const unsigned short* vtb = vt[bufi];
    f32x4 sc[4] = {};
#pragma unroll
    for (int j = 0; j < 4; ++j)
#pragma unroll
      for (int tt = 0; tt < 4; ++tt) {
        bf16x8 kf = *(const bf16x8*)&ktb[(j * 16 + lr) * 128 +
                                         (((tt * 4 + lg) ^ (lr & 7)) << 3)];
        sc[j] =
            __builtin_amdgcn_mfma_f32_16x16x32_bf16(qf[tt], kf, sc[j], 0, 0, 0);
      }
    if (diag) {
      const int kvc = t * 64 + lr;
      const int qg = q0t + w * 16 + lg * 4;
#pragma unroll
      for (int j = 0; j < 4; ++j)
#pragma unroll
        for (int r = 0; r < 4; ++r)
          if (kvc + j * 16 > qg + r) sc[j][r] = -1e30f;
    }
    float resc[4], rs[4];
#pragma unroll
    for (int r = 0; r < 4; ++r) {
      float v = fmaxf(fmaxf(sc[0][r], sc[1][r]), fmaxf(sc[2][r], sc[3][r]));
#pragma unroll
      for (int mk = 1; mk < 16; mk <<= 1) v = fmaxf(v, __shfl_xor(v, mk));
      const float mn = fmaxf(mrow[r], v);
      resc[r] = __expf(mrow[r] - mn);
      mrow[r] = mn;
      rs[r] = 0.f;
    }
#pragma unroll
    for (int j = 0; j < 4; ++j)
#pragma unroll
      for (int r = 0; r < 4; ++r) {
        float p = __expf(sc[j][r] - mrow[r]);
        rs[r] += p;
        const int row = lg * 4 + r;
        const int pchunk = ((j * 2) + (lr >> 3)) ^ (row & 7);
        pw[row * 64 + pchunk * 8 + (lr & 7)] = f2bf(p);
      }
#pragma unroll
    for (int r = 0; r < 4; ++r) {
      float v = rs[r];
#pragma unroll
      for (int mk = 1; mk < 16; mk <<= 1) v += __shfl_xor(v, mk);
      lrow[r] = lrow[r] * resc[r] + v;
    }
#pragma unroll
    for (int f = 0; f < 8; ++f)
#pragma unroll
      for (int r = 0; r < 4; ++r) ao[f][r] *= resc[r];
#pragma unroll
    for (int ks = 0; ks < 2; ++ks) {
      bf16x8 pf =
          *(const bf16x8*)&pw[lr * 64 + (((ks * 4 + lg) ^ (lr & 7)) << 3)];
#pragma unroll
      for (int dj = 0; dj < 8; ++dj) {
        bf16x8 vf = *(const bf16x8*)&vtb[(dj * 16 + lr) * 64 +
                                         (((ks * 4 + lg) ^ (lr & 7)) << 3)];
        ao[dj] =
            __builtin_amdgcn_mfma_f32_16x16x32_bf16(pf, vf, ao[dj], 0, 0, 0);
      }
    }
  };

  stage(0, 0);
  __syncthreads();
  int cur = 0;
  for (int t = 0; t <= xb; ++t) {
    if (t < xb) stage(t + 1, cur ^ 1);
    if (t <= xa)
      process(t, cur, qfA, aoA, mA, lA, &pls[0][w * 1024], q0a, t == xa);
    process(t, cur, qfB, aoB, mB, lB, &pls[1][w * 1024], q0b, t == xb);
    __syncthreads();
    cur ^= 1;
  }

  auto finish = [&](f32x4 (&ao)[8], float (&lrow)[4], int q0t) {
    float inv[4];
#pragma unroll
    for (int r = 0; r < 4; ++r) inv[r] = 1.0f / lrow[r];
#pragma unroll
    for (int dj = 0; dj < 8; ++dj)
#pragma unroll
      for (int r = 0; r < 4; ++r) {
        const int sg = q0t + w * 16 + lg * 4 + r;
        const size_t o =
            ((size_t)b * S_ + sg) * (NH_ * HD_) + h * HD_ + dj * 16 + lr;
        Oa[o] = f2bf(ao[dj][r] * inv[r]);
      }
  };
  finish(aoA, lA, q0a);
  finish(aoB, lB, q0b);
}

extern "C" void kernel_launch(void* const* d_in, const int* in_sizes, int n_in,
                              void* d_out, int out_size, void* d_ws,
                              size_t ws_size, hipStream_t stream) {
  const int* positions = (const int*)d_in[0];
  const float* hidden = (const float*)d_in[1];
  const float* residual = (const float*)d_in[2];
  const float* ln_w = (const float*)d_in[3];
  const float* qkv_w = (const float*)d_in[4];
  const float* o_w = (const float*)d_in[5];
  const float* q_nw = (const float*)d_in[6];
  const float* k_nw = (const float*)d_in[7];

  char* ws = (char*)d_ws;
  const size_t SZ_XN = (size_t)M_ * H_ * 2;            // 16 MiB
  const size_t SZ_QKVW = (size_t)NQKV_ * H_ * 2;       // 16 MiB
  const size_t SZ_OW = (size_t)H_ * (NH_ * HD_) * 2;   // 8 MiB
  const size_t SZ_QKV = (size_t)M_ * NQKV_ * 2;        // 32 MiB
  const size_t SZ_KB = (size_t)B_ * NKV_ * S_ * HD_ * 2;  // 8 MiB
  const size_t SZ_COS = (size_t)B_ * S_ * 64 * 4;      // 1 MiB

  // phase-overlapped layout (regions reused only after their last reader)
  unsigned short* xn = (unsigned short*)(ws);
  unsigned short* q_buf = (unsigned short*)(ws);            // reuse xn
  unsigned short* qkvw_bf = (unsigned short*)(ws + SZ_XN);
  unsigned short* k_buf = (unsigned short*)(ws + SZ_XN);    // reuse qkvw
  unsigned short* v_buf = (unsigned short*)(ws + SZ_XN + SZ_KB);
  unsigned short* owbf = (unsigned short*)(ws + SZ_XN + SZ_QKVW);
  unsigned short* qkv_bf = (unsigned short*)(ws + SZ_XN + SZ_QKVW + SZ_OW);
  unsigned short* attn_o = qkv_bf;                          // reuse qkv
  unsigned short* vt_buf =
      (unsigned short*)(ws + SZ_XN + SZ_QKVW + SZ_OW + SZ_QKV);
  float* cos_t = (float*)(ws + SZ_XN + SZ_QKVW + SZ_OW + SZ_QKV + SZ_KB);
  float* sin_t = (float*)((char*)cos_t + SZ_COS);

  k_rmsnorm<<<M_, 256, 0, stream>>>(hidden, ln_w, xn);
  k_f32_to_bf16<<<2048, 256, 0, stream>>>(qkv_w, qkvw_bf,
                                          (int)(SZ_QKVW / 2 / 4));
  k_f32_to_bf16<<<1024, 256, 0, stream>>>(o_w, owbf, (int)(SZ_OW / 2 / 4));
  k_rope_table<<<(B_ * S_ * 64) / 256, 256, 0, stream>>>(positions, cos_t,
                                                         sin_t);
  k_gemm_bt<0><<<dim3(NQKV_ / 128, M_ / 128), 256, 0, stream>>>(
      xn, qkvw_bf, qkv_bf, nullptr, M_, NQKV_, H_);
  k_postprocess<<<M_, 256, 0, stream>>>(qkv_bf, q_nw, k_nw, cos_t, sin_t,
                                        q_buf, k_buf, v_buf);
  k_transpose_v<<<dim3(S_ / 32, HD_ / 32, B_ * NKV_), 256, 0, stream>>>(v_buf,
                                                                        vt_buf);
  k_attn<<<dim3(16, B_ * NH_), 256, 0, stream>>>(q_buf, k_buf, vt_buf, attn_o);
  k_gemm_bt<1><<<dim3((NH_ * HD_) / 128, M_ / 128), 256, 0, stream>>>(
      attn_o, owbf, d_out, residual, M_, NH_ * HD_, H_);
}

// Round 4
// 262.449 us; speedup vs baseline: 2.1476x; 1.0988x over previous
//
#include <hip/hip_runtime.h>
#include <hip/hip_bf16.h>

typedef __attribute__((ext_vector_type(8))) short bf16x8;
typedef __attribute__((ext_vector_type(4))) float f32x4;

#define B_ 2
#define S_ 2048
#define H_ 2048
#define NH_ 16
#define NKV_ 8
#define HD_ 128
#define M_ (B_ * S_)                   // 4096
#define NQKV_ ((NH_ + 2 * NKV_) * HD_) // 4096
#define QK_SCALE 0.08838834764831845f  // 128^-0.5

#define VMCNT(n) asm volatile("s_waitcnt vmcnt(" #n ")" ::: "memory")

__device__ __forceinline__ unsigned short f2bf(float f) {
  unsigned int u = __float_as_uint(f);
  u += 0x7fffu + ((u >> 16) & 1u);
  return (unsigned short)(u >> 16);
}
__device__ __forceinline__ float bf2f(unsigned short h) {
  return __uint_as_float(((unsigned int)h) << 16);
}
__device__ __forceinline__ void gload_lds16(const void* g, void* l) {
  __builtin_amdgcn_global_load_lds(
      (const __attribute__((address_space(1))) void*)g,
      (__attribute__((address_space(3))) void*)l, 16, 0, 0);
}

// ---------------- phase 1: prep ----------------
__global__ __launch_bounds__(256) void k_rmsnorm(
    const float* __restrict__ x, const float* __restrict__ w,
    unsigned short* __restrict__ out) {
  __shared__ float red[4];
  const int m = blockIdx.x;
  const int t = threadIdx.x;
  const float4* row = (const float4*)(x + (size_t)m * H_);
  float4 v0 = row[t];
  float4 v1 = row[t + 256];
  float ss = v0.x * v0.x + v0.y * v0.y + v0.z * v0.z + v0.w * v0.w +
             v1.x * v1.x + v1.y * v1.y + v1.z * v1.z + v1.w * v1.w;
#pragma unroll
  for (int mk = 1; mk < 64; mk <<= 1) ss += __shfl_xor(ss, mk);
  if ((t & 63) == 0) red[t >> 6] = ss;
  __syncthreads();
  ss = red[0] + red[1] + red[2] + red[3];
  const float sc = rsqrtf(ss * (1.0f / H_) + 1e-6f);
  const float4* wv = (const float4*)w;
  float4 w0 = wv[t], w1 = wv[t + 256];
  ushort4 o0, o1;
  o0.x = f2bf(v0.x * sc * w0.x);
  o0.y = f2bf(v0.y * sc * w0.y);
  o0.z = f2bf(v0.z * sc * w0.z);
  o0.w = f2bf(v0.w * sc * w0.w);
  o1.x = f2bf(v1.x * sc * w1.x);
  o1.y = f2bf(v1.y * sc * w1.y);
  o1.z = f2bf(v1.z * sc * w1.z);
  o1.w = f2bf(v1.w * sc * w1.w);
  ushort4* orow = (ushort4*)(out + (size_t)m * H_);
  orow[t] = o0;
  orow[t + 256] = o1;
}

__global__ __launch_bounds__(256) void k_f32_to_bf16(
    const float* __restrict__ in, unsigned short* __restrict__ out, int n4) {
  int idx = blockIdx.x * 256 + threadIdx.x;
  const int stride = gridDim.x * 256;
  for (; idx < n4; idx += stride) {
    float4 v = ((const float4*)in)[idx];
    ushort4 o;
    o.x = f2bf(v.x);
    o.y = f2bf(v.y);
    o.z = f2bf(v.z);
    o.w = f2bf(v.w);
    ((ushort4*)out)[idx] = o;
  }
}

__global__ __launch_bounds__(256) void k_rope_table(
    const int* __restrict__ positions, float* __restrict__ cos_t,
    float* __restrict__ sin_t) {
  int idx = blockIdx.x * 256 + threadIdx.x;
  if (idx >= B_ * S_ * 64) return;
  int d = idx & 63;
  int bs = idx >> 6;
  float pos = (float)positions[bs];
  float inv_freq = powf(10000.0f, -(float)(2 * d) * (1.0f / HD_));
  float ang = pos * inv_freq;
  cos_t[idx] = cosf(ang);
  sin_t[idx] = sinf(ang);
}

// ---------------- 256x256 8-phase GEMM (QKV) ----------------
// A [M][K] bf16 x Bt [N][K] bf16 -> C [M][N] bf16.
// T2 XOR-swizzle (chunk d = p ^ (row&7), both-sides involution, rule #21),
// T3/T4 phased schedule with counted vmcnt (never 0 in steady state),
// T5 setprio around each 16-MFMA cluster.
template <int FMB, int FNB>
__device__ __forceinline__ void phase_loads(const unsigned short* sAb,
                                            const unsigned short* sBb, int wm,
                                            int wn, int lr, int lg,
                                            bf16x8 (&af)[2][4],
                                            bf16x8 (&bfv)[2][2]) {
#pragma unroll
  for (int kk = 0; kk < 2; ++kk) {
    const int pc = kk * 4 + lg;
#pragma unroll
    for (int i = 0; i < 4; ++i) {
      const int row = wm + (FMB + i) * 16 + lr;
      af[kk][i] = *(const bf16x8*)&sAb[row * 64 + ((pc ^ (row & 7)) << 3)];
    }
#pragma unroll
    for (int j = 0; j < 2; ++j) {
      const int row = wn + (FNB + j) * 16 + lr;
      bfv[kk][j] = *(const bf16x8*)&sBb[row * 64 + ((pc ^ (row & 7)) << 3)];
    }
  }
}

template <int FMB, int FNB>
__device__ __forceinline__ void phase_mfma(const bf16x8 (&af)[2][4],
                                           const bf16x8 (&bfv)[2][2],
                                           f32x4 (&acc)[8][4]) {
#pragma unroll
  for (int kk = 0; kk < 2; ++kk)
#pragma unroll
    for (int i = 0; i < 4; ++i)
#pragma unroll
      for (int j = 0; j < 2; ++j)
        acc[FMB + i][FNB + j] = __builtin_amdgcn_mfma_f32_16x16x32_bf16(
            af[kk][i], bfv[kk][j], acc[FMB + i][FNB + j], 0, 0, 0);
}

__global__ __launch_bounds__(512, 2) void k_gemm256(
    const unsigned short* __restrict__ A, const unsigned short* __restrict__ Bt,
    unsigned short* __restrict__ C, int M, int N, int K) {
  __shared__ unsigned short sA[2][256 * 64];
  __shared__ unsigned short sB[2][256 * 64];
  const int tid = threadIdx.x;
  const int w = tid >> 6;
  const int l = tid & 63;
  const int lr = l & 15, lg = l >> 4;
  const int m0 = blockIdx.y * 256, n0 = blockIdx.x * 256;
  const int wm = (w >> 2) * 128, wn = (w & 3) * 64;
  f32x4 acc[8][4] = {};

  // stage half-tile h of K-tile t into buf: h=0/1 -> A rows 0-127/128-255,
  // h=2/3 -> B rows 0-127/128-255. Linear LDS dest, pre-swizzled global src.
  auto stageH = [&](int t, int bufi, int h) {
    const int k0 = t * 64;
    const unsigned short* src = (h < 2) ? A : Bt;
    unsigned short* dst = (h < 2) ? sA[bufi] : sB[bufi];
    const int rbase = (h & 1) * 128;
    const size_t gbase = (h < 2) ? (size_t)m0 : (size_t)n0;
#pragma unroll
    for (int i = 0; i < 2; ++i) {
      const int L = i * 512 + tid;      // chunk 0..1023 within half-tile
      const int r = L >> 3;             // local row 0..127
      const int p = L & 7;              // dest chunk pos in row
      const int d = p ^ (r & 7);        // swizzled source chunk
      gload_lds16(src + (gbase + rbase + r) * (size_t)K + k0 + d * 8,
                  (char*)dst + (size_t)rbase * 128 +
                      (size_t)(i * 512 + w * 64) * 16);
    }
  };

#define GPHASE(FMB, FNB, HSTAGE)                                        \
  {                                                                     \
    bf16x8 af[2][4];                                                    \
    bf16x8 bfv[2][2];                                                   \
    phase_loads<FMB, FNB>(sA[bufi], sB[bufi], wm, wn, lr, lg, af, bfv); \
    if (st) stageH(t + 1, bufi ^ 1, HSTAGE);                            \
    __builtin_amdgcn_s_barrier();                                       \
    asm volatile("s_waitcnt lgkmcnt(0)" ::: "memory");                  \
    __builtin_amdgcn_sched_barrier(0);                                  \
    __builtin_amdgcn_s_setprio(1);                                      \
    phase_mfma<FMB, FNB>(af, bfv, acc);                                 \
    __builtin_amdgcn_s_setprio(0);                                      \
  }

  // prologue: stage all 4 half-tiles of tile 0; A0,A1,B0 must be resident.
  stageH(0, 0, 0);
  stageH(0, 0, 1);
  stageH(0, 0, 2);
  stageH(0, 0, 3);
  VMCNT(2);
  __builtin_amdgcn_s_barrier();
  __builtin_amdgcn_sched_barrier(0);

  const int NT = K >> 6;
  for (int t = 0; t < NT; ++t) {
    const int bufi = t & 1;
    const bool st = (t + 1 < NT);
    GPHASE(0, 0, 0);
    __builtin_amdgcn_s_barrier();
    __builtin_amdgcn_sched_barrier(0);
    GPHASE(4, 0, 1);
    if (st) {
      VMCNT(4);   // B1(t) landed (oldest of 6 outstanding)
    } else {
      VMCNT(0);
    }
    __builtin_amdgcn_s_barrier();
    __builtin_amdgcn_sched_barrier(0);
    GPHASE(4, 2, 2);
    __builtin_amdgcn_s_barrier();
    __builtin_amdgcn_sched_barrier(0);
    GPHASE(0, 2, 3);
    if (st) VMCNT(2);  // A0,A1,B0(t+1) landed; B1(t+1) may fly
    __builtin_amdgcn_s_barrier();
    __builtin_amdgcn_sched_barrier(0);
  }
#undef GPHASE

#pragma unroll
  for (int fm = 0; fm < 8; ++fm)
#pragma unroll
    for (int fn = 0; fn < 4; ++fn)
#pragma unroll
      for (int r = 0; r < 4; ++r) {
        const int row = m0 + wm + fm * 16 + lg * 4 + r;
        const int col = n0 + wn + fn * 16 + lr;
        C[(size_t)row * N + col] = f2bf(acc[fm][fn][r]);
      }
}

// ---------------- 128x128 GEMM (O-proj: f32 out += resid) ----------
__global__ __launch_bounds__(256) void k_gemm_bt_res(
    const unsigned short* __restrict__ A, const unsigned short* __restrict__ Bt,
    float* __restrict__ Cout, const float* __restrict__ resid, int M, int N,
    int K) {
  __shared__ unsigned short sA[128 * 64];
  __shared__ unsigned short sB[128 * 64];
  const int tid = threadIdx.x;
  const int w = tid >> 6, l = tid & 63;
  const int lr = l & 15, lg = l >> 4;
  const int m0 = blockIdx.y * 128, n0 = blockIdx.x * 128;
  const int wm = (w >> 1) * 64, wn = (w & 1) * 64;
  f32x4 acc[4][4] = {};
  for (int k0 = 0; k0 < K; k0 += 64) {
#pragma unroll
    for (int i = 0; i < 4; ++i) {
      const int chunk = i * 256 + tid;
      const int row = chunk >> 3;
      const int off = (chunk & 7) * 8;
      gload_lds16(A + (size_t)(m0 + row) * K + (k0 + off),
                  (char*)sA + (size_t)(i * 256 + w * 64) * 16);
      gload_lds16(Bt + (size_t)(n0 + row) * K + (k0 + off),
                  (char*)sB + (size_t)(i * 256 + w * 64) * 16);
    }
    __syncthreads();
#pragma unroll
    for (int kk = 0; kk < 64; kk += 32) {
      bf16x8 af[4], bfr[4];
#pragma unroll
      for (int i = 0; i < 4; ++i)
        af[i] = *(const bf16x8*)&sA[(wm + i * 16 + lr) * 64 + kk + lg * 8];
#pragma unroll
      for (int j = 0; j < 4; ++j)
        bfr[j] = *(const bf16x8*)&sB[(wn + j * 16 + lr) * 64 + kk + lg * 8];
#pragma unroll
      for (int i = 0; i < 4; ++i)
#pragma unroll
        for (int j = 0; j < 4; ++j)
          acc[i][j] = __builtin_amdgcn_mfma_f32_16x16x32_bf16(af[i], bfr[j],
                                                              acc[i][j], 0, 0, 0);
    }
    __syncthreads();
  }
#pragma unroll
  for (int i = 0; i < 4; ++i)
#pragma unroll
    for (int j = 0; j < 4; ++j)
#pragma unroll
      for (int r = 0; r < 4; ++r) {
        const int row = m0 + wm + i * 16 + lg * 4 + r;
        const int col = n0 + wn + j * 16 + lr;
        const size_t o = (size_t)row * N + col;
        Cout[o] = acc[i][j][r] + resid[o];
      }
}

// ---------------- phase 3: q/k norm + rope, split ----------------
__global__ __launch_bounds__(256) void k_postprocess(
    const unsigned short* __restrict__ qkv, const float* __restrict__ qw,
    const float* __restrict__ kw, const float* __restrict__ cos_t,
    const float* __restrict__ sin_t, unsigned short* __restrict__ qb,
    unsigned short* __restrict__ kb, unsigned short* __restrict__ vb) {
  const int m = blockIdx.x;
  const int b = m >> 11, s = m & (S_ - 1);
  const int w = threadIdx.x >> 6, l = threadIdx.x & 63;
  const unsigned short* row = qkv + (size_t)m * NQKV_;
  const float c = cos_t[(size_t)m * 64 + l];
  const float sn = sin_t[(size_t)m * 64 + l];
  for (int hh = w * 8; hh < w * 8 + 8; ++hh) {
    int base, type;
    unsigned short* out;
    const float* nw;
    if (hh < NH_) {
      type = 0;
      base = hh * HD_;
      out = qb + ((size_t)(b * NH_ + hh) * S_ + s) * HD_;
      nw = qw;
    } else if (hh < NH_ + NKV_) {
      int kh = hh - NH_;
      type = 1;
      base = NH_ * HD_ + kh * HD_;
      out = kb + ((size_t)(b * NKV_ + kh) * S_ + s) * HD_;
      nw = kw;
    } else {
      int kh = hh - NH_ - NKV_;
      type = 2;
      base = (NH_ + NKV_) * HD_ + kh * HD_;
      out = vb + ((size_t)(b * NKV_ + kh) * S_ + s) * HD_;
      nw = nullptr;
    }
    unsigned short r1 = row[base + l];
    unsigned short r2 = row[base + 64 + l];
    if (type == 2) {
      out[l] = r1;
      out[64 + l] = r2;
      continue;
    }
    float x1 = bf2f(r1), x2 = bf2f(r2);
    float ss = x1 * x1 + x2 * x2;
#pragma unroll
    for (int mk = 1; mk < 64; mk <<= 1) ss += __shfl_xor(ss, mk);
    float sc = rsqrtf(ss * (1.0f / HD_) + 1e-6f);
    float y1 = x1 * sc * nw[l];
    float y2 = x2 * sc * nw[64 + l];
    float o1 = y1 * c - y2 * sn;
    float o2 = y2 * c + y1 * sn;
    if (type == 0) {
      o1 *= QK_SCALE;
      o2 *= QK_SCALE;
    }
    out[l] = f2bf(o1);
    out[64 + l] = f2bf(o2);
  }
}

// ---------------- phase 3b: V -> V^T ----------------
__global__ __launch_bounds__(256) void k_transpose_v(
    const unsigned short* __restrict__ in,  // [BH][S][HD]
    unsigned short* __restrict__ out) {     // [BH][HD][S]
  __shared__ unsigned short tile[32][33];
  const int bx = blockIdx.x, by = blockIdx.y, bz = blockIdx.z;
  const unsigned short* src = in + (size_t)bz * S_ * HD_;
  unsigned short* dst = out + (size_t)bz * S_ * HD_;
  const int tx = threadIdx.x & 31, ty = threadIdx.x >> 5;
#pragma unroll
  for (int i = ty; i < 32; i += 8)
    tile[i][tx] = src[(size_t)(bx * 32 + i) * HD_ + by * 32 + tx];
  __syncthreads();
#pragma unroll
  for (int i = ty; i < 32; i += 8)
    dst[(size_t)(by * 32 + i) * S_ + bx * 32 + tx] = tile[tx][i];
}

// ---------------- phase 4: causal GQA flash attention ----------------
__global__ __launch_bounds__(256, 2) void k_attn(
    const unsigned short* __restrict__ Q,   // [B*NH][S][HD] (pre-scaled)
    const unsigned short* __restrict__ K,   // [B*NKV][S][HD]
    const unsigned short* __restrict__ VT,  // [B*NKV][HD][S]
    unsigned short* __restrict__ Oa) {      // [M][NH*HD]
  __shared__ unsigned short kt[2][64 * 128];
  __shared__ unsigned short vt[2][128 * 64];
  __shared__ unsigned short pls[2][4 * 16 * 64];
  const int bh = blockIdx.y;
  const int b = bh >> 4, h = bh & 15;
  const int kvh = b * NKV_ + (h >> 1);
  const int xa = blockIdx.x;       // 0..15
  const int xb = 31 - xa;          // 16..31
  const int q0a = xa * 64, q0b = xb * 64;
  const int w = threadIdx.x >> 6, l = threadIdx.x & 63;
  const int lr = l & 15, lg = l >> 4;

  bf16x8 qfA[4], qfB[4];
  {
    const unsigned short* Qp = Q + ((size_t)bh * S_ + q0a + w * 16) * HD_;
#pragma unroll
    for (int tt = 0; tt < 4; ++tt)
      qfA[tt] = *(const bf16x8*)(Qp + (size_t)lr * HD_ + tt * 32 + lg * 8);
  }
  {
    const unsigned short* Qp = Q + ((size_t)bh * S_ + q0b + w * 16) * HD_;
#pragma unroll
    for (int tt = 0; tt < 4; ++tt)
      qfB[tt] = *(const bf16x8*)(Qp + (size_t)lr * HD_ + tt * 32 + lg * 8);
  }
  f32x4 aoA[8] = {}, aoB[8] = {};
  float mA[4], lA[4], mB[4], lB[4];
#pragma unroll
  for (int r = 0; r < 4; ++r) {
    mA[r] = -1e30f;
    lA[r] = 0.f;
    mB[r] = -1e30f;
    lB[r] = 0.f;
  }
  const unsigned short* Kp = K + (size_t)kvh * S_ * HD_;
  const unsigned short* Vp = VT + (size_t)kvh * HD_ * S_;

  auto stage = [&](int t, int bufi) {
    const int k0 = t * 64;
#pragma unroll
    for (int i = 0; i < 4; ++i) {
      const int chunk = i * 256 + threadIdx.x;
      {
        const int r = chunk >> 4, p = chunk & 15;
        const int d = p ^ (r & 7);
        gload_lds16(Kp + (size_t)(k0 + r) * HD_ + d * 8,
                    (char*)kt[bufi] + (size_t)(i * 256 + w * 64) * 16);
      }
      {
        const int r = chunk >> 3, p = chunk & 7;
        const int d = p ^ (r & 7);
        gload_lds16(Vp + (size_t)r * S_ + k0 + d * 8,
                    (char*)vt[bufi] + (size_t)(i * 256 + w * 64) * 16);
      }
    }
  };

  auto process = [&](int t, int bufi, const bf16x8 (&qf)[4], f32x4 (&ao)[8],
                     float (&mrow)[4], float (&lrow)[4], unsigned short* pw,
                     int q0t, bool diag) {
    const unsigned short* ktb = kt[bufi];
    const unsigned short* vtb = vt[bufi];
    f32x4 sc[4] = {};
#pragma unroll
    for (int j = 0; j < 4; ++j)
#pragma unroll
      for (int tt = 0; tt < 4; ++tt) {
        bf16x8 kf = *(const bf16x8*)&ktb[(j * 16 + lr) * 128 +
                                         (((tt * 4 + lg) ^ (lr & 7)) << 3)];
        sc[j] =
            __builtin_amdgcn_mfma_f32_16x16x32_bf16(qf[tt], kf, sc[j], 0, 0, 0);
      }
    if (diag) {
      const int kvc = t * 64 + lr;
      const int qg = q0t + w * 16 + lg * 4;
#pragma unroll
      for (int j = 0; j < 4; ++j)
#pragma unroll
        for (int r = 0; r < 4; ++r)
          if (kvc + j * 16 > qg + r) sc[j][r] = -1e30f;
    }
    float resc[4], rs[4];
#pragma unroll
    for (int r = 0; r < 4; ++r) {
      float v = fmaxf(fmaxf(sc[0][r], sc[1][r]), fmaxf(sc[2][r], sc[3][r]));
#pragma unroll
      for (int mk = 1; mk < 16; mk <<= 1) v = fmaxf(v, __shfl_xor(v, mk));
      const float mn = fmaxf(mrow[r], v);
      resc[r] = __expf(mrow[r] - mn);
      mrow[r] = mn;
      rs[r] = 0.f;
    }
#pragma unroll
    for (int j = 0; j < 4; ++j)
#pragma unroll
      for (int r = 0; r < 4; ++r) {
        float p = __expf(sc[j][r] - mrow[r]);
        rs[r] += p;
        const int row = lg * 4 + r;
        const int pchunk = ((j * 2) + (lr >> 3)) ^ (row & 7);
        pw[row * 64 + pchunk * 8 + (lr & 7)] = f2bf(p);
      }
#pragma unroll
    for (int r = 0; r < 4; ++r) {
      float v = rs[r];
#pragma unroll
      for (int mk = 1; mk < 16; mk <<= 1) v += __shfl_xor(v, mk);
      lrow[r] = lrow[r] * resc[r] + v;
    }
#pragma unroll
    for (int f = 0; f < 8; ++f)
#pragma unroll
      for (int r = 0; r < 4; ++r) ao[f][r] *= resc[r];
#pragma unroll
    for (int ks = 0; ks < 2; ++ks) {
      bf16x8 pf =
          *(const bf16x8*)&pw[lr * 64 + (((ks * 4 + lg) ^ (lr & 7)) << 3)];
#pragma unroll
      for (int dj = 0; dj < 8; ++dj) {
        bf16x8 vf = *(const bf16x8*)&vtb[(dj * 16 + lr) * 64 +
                                         (((ks * 4 + lg) ^ (lr & 7)) << 3)];
        ao[dj] =
            __builtin_amdgcn_mfma_f32_16x16x32_bf16(pf, vf, ao[dj], 0, 0, 0);
      }
    }
  };

  stage(0, 0);
  __syncthreads();
  int cur = 0;
  for (int t = 0; t <= xb; ++t) {
    if (t < xb) stage(t + 1, cur ^ 1);
    if (t <= xa)
      process(t, cur, qfA, aoA, mA, lA, &pls[0][w * 1024], q0a, t == xa);
    process(t, cur, qfB, aoB, mB, lB, &pls[1][w * 1024], q0b, t == xb);
    __syncthreads();
    cur ^= 1;
  }

  auto finish = [&](f32x4 (&ao)[8], float (&lrow)[4], int q0t) {
    float inv[4];
#pragma unroll
    for (int r = 0; r < 4; ++r) inv[r] = 1.0f / lrow[r];
#pragma unroll
    for (int dj = 0; dj < 8; ++dj)
#pragma unroll
      for (int r = 0; r < 4; ++r) {
        const int sg = q0t + w * 16 + lg * 4 + r;
        const size_t o =
            ((size_t)b * S_ + sg) * (NH_ * HD_) + h * HD_ + dj * 16 + lr;
        Oa[o] = f2bf(ao[dj][r] * inv[r]);
      }
  };
  finish(aoA, lA, q0a);
  finish(aoB, lB, q0b);
}

extern "C" void kernel_launch(void* const* d_in, const int* in_sizes, int n_in,
                              void* d_out, int out_size, void* d_ws,
                              size_t ws_size, hipStream_t stream) {
  const int* positions = (const int*)d_in[0];
  const float* hidden = (const float*)d_in[1];
  const float* residual = (const float*)d_in[2];
  const float* ln_w = (const float*)d_in[3];
  const float* qkv_w = (const float*)d_in[4];
  const float* o_w = (const float*)d_in[5];
  const float* q_nw = (const float*)d_in[6];
  const float* k_nw = (const float*)d_in[7];

  char* ws = (char*)d_ws;
  const size_t SZ_XN = (size_t)M_ * H_ * 2;            // 16 MiB
  const size_t SZ_QKVW = (size_t)NQKV_ * H_ * 2;       // 16 MiB
  const size_t SZ_OW = (size_t)H_ * (NH_ * HD_) * 2;   // 8 MiB
  const size_t SZ_QKV = (size_t)M_ * NQKV_ * 2;        // 32 MiB
  const size_t SZ_KB = (size_t)B_ * NKV_ * S_ * HD_ * 2;  // 8 MiB
  const size_t SZ_COS = (size_t)B_ * S_ * 64 * 4;      // 1 MiB

  unsigned short* xn = (unsigned short*)(ws);
  unsigned short* q_buf = (unsigned short*)(ws);            // reuse xn
  unsigned short* qkvw_bf = (unsigned short*)(ws + SZ_XN);
  unsigned short* k_buf = (unsigned short*)(ws + SZ_XN);    // reuse qkvw
  unsigned short* v_buf = (unsigned short*)(ws + SZ_XN + SZ_KB);
  unsigned short* owbf = (unsigned short*)(ws + SZ_XN + SZ_QKVW);
  unsigned short* qkv_bf = (unsigned short*)(ws + SZ_XN + SZ_QKVW + SZ_OW);
  unsigned short* attn_o = qkv_bf;                          // reuse qkv
  unsigned short* vt_buf =
      (unsigned short*)(ws + SZ_XN + SZ_QKVW + SZ_OW + SZ_QKV);
  float* cos_t = (float*)(ws + SZ_XN + SZ_QKVW + SZ_OW + SZ_QKV + SZ_KB);
  float* sin_t = (float*)((char*)cos_t + SZ_COS);

  k_rmsnorm<<<M_, 256, 0, stream>>>(hidden, ln_w, xn);
  k_f32_to_bf16<<<2048, 256, 0, stream>>>(qkv_w, qkvw_bf,
                                          (int)(SZ_QKVW / 2 / 4));
  k_f32_to_bf16<<<1024, 256, 0, stream>>>(o_w, owbf, (int)(SZ_OW / 2 / 4));
  k_rope_table<<<(B_ * S_ * 64) / 256, 256, 0, stream>>>(positions, cos_t,
                                                         sin_t);
  k_gemm256<<<dim3(NQKV_ / 256, M_ / 256), 512, 0, stream>>>(
      xn, qkvw_bf, qkv_bf, M_, NQKV_, H_);
  k_postprocess<<<M_, 256, 0, stream>>>(qkv_bf, q_nw, k_nw, cos_t, sin_t,
                                        q_buf, k_buf, v_buf);
  k_transpose_v<<<dim3(S_ / 32, HD_ / 32, B_ * NKV_), 256, 0, stream>>>(v_buf,
                                                                        vt_buf);
  k_attn<<<dim3(16, B_ * NH_), 256, 0, stream>>>(q_buf, k_buf, vt_buf, attn_o);
  k_gemm_bt_res<<<dim3((NH_ * HD_) / 128, M_ / 128), 256, 0, stream>>>(
      attn_o, owbf, (float*)d_out, residual, M_, NH_ * HD_, H_);
}